// Round 6
// baseline (323.835 us; speedup 1.0000x reference)
//
#include <hip/hip_runtime.h>
#include <hip/hip_bf16.h>
#include <stdint.h>

// GatheringLoss: score = q[32768x512] @ items[4096x512]^T, idx = argmax_row,
// out = mean((q - items[idx])^2).
// R6: fix R5's LDS-pipe + sync bound. 32x32x16 MFMA (half LDS bytes/FLOP),
// A (q) full-K resident in LDS (128KB, staged once, XOR-8 swizzle), B chunk
// 512 cols x 16 K as [2 kslot][512 col] 16B units (natural ~2-way banks),
// dbuf 2x16KB. 8 waves 2Mx4N: af[2]+bf[4]=6 b128 -> 8 MFMA(32K FLOP).
// 256 iterations (8 col-groups x 32 kc). Argmax: per-lane running
// (max,idx)[2][16], group fold in-register; single butterfly + LDS merge at
// block end (sV/sI reuses B buffers).
//
// ws: [0,32MB) q_fp16 | [+4MB) items_fp16 | [+128KB) idx[32768] i32
//     | [+1KB) partials[256]

#define D_DIM 512
#define M_ITEMS 4096
#define N_ROWS 32768
#define BM 128
#define GCOLS 512            // cols per group (B chunk width)
#define NG (M_ITEMS / GCOLS) // 8 groups
#define NKC (D_DIM / 16)     // 32 k-chunks per group
#define TOT (NG * NKC)       // 256 iterations
#define MROWS 128

typedef _Float16 half8 __attribute__((ext_vector_type(8)));
typedef _Float16 half4h __attribute__((ext_vector_type(4)));
typedef float f32x16 __attribute__((ext_vector_type(16)));

#define GLD_LDS16(g, l)                                                        \
  __builtin_amdgcn_global_load_lds(                                            \
      (__attribute__((address_space(1))) const void*)(g),                      \
      (__attribute__((address_space(3))) void*)(l), 16, 0, 0)

#define BAR() __builtin_amdgcn_s_barrier()
#define SCHEDB() __builtin_amdgcn_sched_barrier(0)
#define VMW0() asm volatile("s_waitcnt vmcnt(0)" ::: "memory")

__global__ __launch_bounds__(256) void cast_f32_f16(
    const float* __restrict__ in, _Float16* __restrict__ out, int n4) {
  const int stride = gridDim.x * blockDim.x;
  for (int i = blockIdx.x * blockDim.x + threadIdx.x; i < n4; i += stride) {
    const float4 v = reinterpret_cast<const float4*>(in)[i];
    half4h h;
    h.x = (_Float16)v.x;
    h.y = (_Float16)v.y;
    h.z = (_Float16)v.z;
    h.w = (_Float16)v.w;
    reinterpret_cast<half4h*>(out)[i] = h;
  }
}

// Stage B chunk J (group J>>5, kc J&31) into Blds[buf]: 512 threads x 2 x 16B.
// Unit (s,c) at elem (s*512+c)*8 holds items[g*512+c][kc*16 + s*8 .. +8).
#define STAGE_B(J, buf)                                                        \
  do {                                                                         \
    const int g_ = (J) >> 5, kc_ = (J) & 31;                                   \
    const _Float16* src_ = ih + (size_t)(g_ * 512 + t) * D_DIM + kc_ * 16;     \
    GLD_LDS16(src_, &Blds[buf][0] + t * 8);                                    \
    GLD_LDS16(src_ + 8, &Blds[buf][0] + 4096 + t * 8);                         \
  } while (0)

__global__ __launch_bounds__(512, 2) void score_argmax(
    const _Float16* __restrict__ qh, const _Float16* __restrict__ ih,
    int* __restrict__ idxArr) {
  __shared__ _Float16 Alds[BM * D_DIM]; // 128 KiB, full-K A, XOR-8 swizzled
  __shared__ _Float16 Blds[2][2 * 512 * 8]; // 2 x 16 KiB

  const int t = threadIdx.x; // 0..511
  const int lane = t & 63;
  const int wid = t >> 6;  // 0..7
  const int wm = wid >> 2; // 0..1 (row half: 64 rows)
  const int wn = wid & 3;  // 0..3 (col quarter of 512: 128 cols)
  const int l31 = lane & 31;
  const int hsel = lane >> 5; // 0..1
  const int l7 = lane & 7;

  // T1: XCD chunking (grid 256 = 8 XCD x 32)
  const int bid = blockIdx.x;
  const int rb = (bid & 7) * 32 + (bid >> 3);
  const int row0 = rb * BM;

  // --- stage A once (16 x 16B/thread = 128KB), swizzled: LDS slot (row,s)
  // holds global k-group s^(row&7). Per-GLD row is wave-uniform, slot=lane.
#pragma unroll
  for (int i = 0; i < 16; ++i) {
    const int f = i * 512 + t;
    const int r = f >> 6;
    const int s = f & 63;
    GLD_LDS16(qh + (size_t)(row0 + r) * D_DIM + ((s ^ (r & 7)) * 8),
              (_Float16*)Alds + (size_t)f * 8);
  }
  STAGE_B(0, 0);

  f32x16 acc[2][4];
#pragma unroll
  for (int fr = 0; fr < 2; ++fr)
#pragma unroll
    for (int fc = 0; fc < 4; ++fc) acc[fr][fc] = (f32x16)(0.0f);
  float rmax[2][16];
  int ridx[2][16];
#pragma unroll
  for (int fr = 0; fr < 2; ++fr)
#pragma unroll
    for (int rg = 0; rg < 16; ++rg) {
      rmax[fr][rg] = -3.0e38f;
      ridx[fr][rg] = 0;
    }

  // A-frag row element-offsets (row*512), fr=0,1; row = wm*64+fr*32+l31
  const int arow0 = (wm * 64 + l31) * D_DIM;
  const int arow1 = (wm * 64 + 32 + l31) * D_DIM;

#pragma unroll 1
  for (int J = 0; J < TOT; ++J) {
    VMW0(); // my stage of buf[J&1] (issued last iter) complete
    BAR();  // all waves' stages landed; all readers of buf[(J+1)&1] done
    SCHEDB();
    if (J + 1 < TOT) STAGE_B(J + 1, (J + 1) & 1);

    const int kc = J & 31;
    const _Float16* Bb = &Blds[J & 1][0];
    // A frags: k-group g = kc*2 + hsel, slot = g ^ (row&7); row&7 == l7
    const int aslot = ((kc * 2 + hsel) ^ l7) * 8;
    half8 af[2], bf[4];
    af[0] = *(const half8*)(Alds + arow0 + aslot);
    af[1] = *(const half8*)(Alds + arow1 + aslot);
#pragma unroll
    for (int fc = 0; fc < 4; ++fc) {
      const int c = wn * 128 + fc * 32 + l31;
      bf[fc] = *(const half8*)(Bb + (size_t)(hsel * 512 + c) * 8);
    }
#pragma unroll
    for (int fr = 0; fr < 2; ++fr)
#pragma unroll
      for (int fc = 0; fc < 4; ++fc)
        acc[fr][fc] = __builtin_amdgcn_mfma_f32_32x32x16_f16(
            af[fr], bf[fc], acc[fr][fc], 0, 0, 0);

    if (kc == 31) { // group complete: fold into per-lane running (max,idx)
      const int colbase = (J >> 5) * GCOLS + wn * 128 + l31;
#pragma unroll
      for (int fr = 0; fr < 2; ++fr)
#pragma unroll
        for (int rg = 0; rg < 16; ++rg) {
          float v = acc[fr][0][rg];
          int c = colbase;
#pragma unroll
          for (int fc = 1; fc < 4; ++fc) {
            const float vv = acc[fr][fc][rg];
            if (vv > v) { // cols ascend with fc: strict > keeps lowest
              v = vv;
              c = colbase + fc * 32;
            }
          }
          if (v > rmax[fr][rg]) { // groups ascend: strict > keeps lowest
            rmax[fr][rg] = v;
            ridx[fr][rg] = c;
          }
        }
#pragma unroll
      for (int fr = 0; fr < 2; ++fr)
#pragma unroll
        for (int fc = 0; fc < 4; ++fc) acc[fr][fc] = (f32x16)(0.0f);
    }
  }

  // --- block end: butterfly-reduce each (fr,rg) entry across the 32 col
  // lanes; lane picks its entry e = lane&31. C/D layout (m74/m101): col =
  // lane&31, row = (rg&3) + 8*(rg>>2) + 4*(lane>>5).
  float bv = -3.0e38f;
  int bi = 0;
#pragma unroll
  for (int fr = 0; fr < 2; ++fr)
#pragma unroll
    for (int rg = 0; rg < 16; ++rg) {
      float v = rmax[fr][rg];
      int c = ridx[fr][rg];
#pragma unroll
      for (int m = 1; m < 32; m <<= 1) {
        const float ov = __shfl_xor(v, m, 64);
        const int oc = __shfl_xor(c, m, 64);
        if (ov > v || (ov == v && oc < c)) {
          v = ov;
          c = oc;
        }
      }
      if (l31 == fr * 16 + rg) {
        bv = v;
        bi = c;
      }
    }
  const int e = l31;
  const int row_local =
      wm * 64 + (e >> 4) * 32 + ((e & 3) + 8 * ((e >> 2) & 3)) + 4 * hsel;

  // wn-merge via LDS (reuse B buffers; all buf0 reads done after last BAR,
  // buf1 readers are other waves' J=255 compute which only touches buf1).
  float* sV = (float*)&Blds[0][0];     // [4][128]
  int* sI = (int*)(sV + 4 * BM);       // [4][128]
  sV[wn * BM + row_local] = bv;
  sI[wn * BM + row_local] = bi;
  __syncthreads();
  if (t < BM) {
    float fv = sV[t];
    int fi = sI[t];
#pragma unroll
    for (int w = 1; w < 4; ++w) {
      const float v = sV[w * BM + t];
      const int ii = sI[w * BM + t];
      if (v > fv || (v == fv && ii < fi)) {
        fv = v;
        fi = ii;
      }
    }
    idxArr[row0 + t] = fi;
  }
}

__global__ __launch_bounds__(256) void gather_mse(
    const float* __restrict__ qf, const float* __restrict__ itf,
    const int* __restrict__ idxArr, float* __restrict__ partials) {
  __shared__ float sSum[4];
  const int t = threadIdx.x;
  const int lane = t & 63;
  const int wv = t >> 6;
  const int row0 = blockIdx.x * MROWS;

  float lsum = 0.0f;
  for (int rr = 0; rr < 32; ++rr) {
    const int row = row0 + wv * 32 + rr;
    const int bi = idxArr[row];
    const float* qr = qf + (size_t)row * D_DIM + lane * 8;
    const float* gr = itf + (size_t)bi * D_DIM + lane * 8;
    const float4 a0 = reinterpret_cast<const float4*>(qr)[0];
    const float4 a1 = reinterpret_cast<const float4*>(qr)[1];
    const float4 b0 = reinterpret_cast<const float4*>(gr)[0];
    const float4 b1 = reinterpret_cast<const float4*>(gr)[1];
    const float d0 = a0.x - b0.x, d1 = a0.y - b0.y;
    const float d2 = a0.z - b0.z, d3 = a0.w - b0.w;
    const float d4 = a1.x - b1.x, d5 = a1.y - b1.y;
    const float d6 = a1.z - b1.z, d7 = a1.w - b1.w;
    lsum += d0 * d0 + d1 * d1 + d2 * d2 + d3 * d3 + d4 * d4 + d5 * d5 +
            d6 * d6 + d7 * d7;
  }
#pragma unroll
  for (int m = 1; m < 64; m <<= 1) lsum += __shfl_xor(lsum, m, 64);
  if (lane == 0) sSum[wv] = lsum;
  __syncthreads();
  if (t == 0) partials[blockIdx.x] = sSum[0] + sSum[1] + sSum[2] + sSum[3];
}

__global__ __launch_bounds__(256) void final_reduce(
    const float* __restrict__ partials, float* __restrict__ out) {
  __shared__ float sS[4];
  const int t = threadIdx.x;
  float v = partials[t]; // exactly 256 partials
#pragma unroll
  for (int m = 1; m < 64; m <<= 1) v += __shfl_xor(v, m, 64);
  if ((t & 63) == 0) sS[t >> 6] = v;
  __syncthreads();
  if (t == 0)
    out[0] = (sS[0] + sS[1] + sS[2] + sS[3]) *
             (1.0f / ((float)N_ROWS * (float)D_DIM));
}

extern "C" void kernel_launch(void* const* d_in, const int* in_sizes, int n_in,
                              void* d_out, int out_size, void* d_ws,
                              size_t ws_size, hipStream_t stream) {
  const float* qf = (const float*)d_in[0];  // [32768][512]
  const float* itf = (const float*)d_in[1]; // [4096][512]
  char* ws = (char*)d_ws;
  _Float16* qh = (_Float16*)ws;                                // 32 MB
  _Float16* ih = (_Float16*)(ws + (size_t)N_ROWS * D_DIM * 2); // 4 MB
  char* p = ws + (size_t)N_ROWS * D_DIM * 2 + (size_t)M_ITEMS * D_DIM * 2;
  int* idxArr = (int*)p;                                       // 128 KB
  float* partials = (float*)(p + (size_t)N_ROWS * 4);          // 1 KB
  float* out = (float*)d_out;

  cast_f32_f16<<<2048, 256, 0, stream>>>(qf, qh, N_ROWS * D_DIM / 4);
  cast_f32_f16<<<512, 256, 0, stream>>>(itf, ih, M_ITEMS * D_DIM / 4);
  score_argmax<<<N_ROWS / BM, 512, 0, stream>>>(qh, ih, idxArr);
  gather_mse<<<N_ROWS / MROWS, 256, 0, stream>>>(qf, itf, idxArr, partials);
  final_reduce<<<1, 256, 0, stream>>>(partials, out);
}

// Round 7
// 260.762 us; speedup vs baseline: 1.2419x; 1.2419x over previous
//
#include <hip/hip_runtime.h>
#include <hip/hip_bf16.h>
#include <stdint.h>

// GatheringLoss: score = q[32768x512] @ items[4096x512]^T, idx = argmax_row,
// out = mean((q - items[idx])^2).
// R7: R6 structure (A full-K resident 128KB XOR-8 swizzled, 32x32x16 MFMA,
// B chunks 512col x 16K dbuf, 256 iters) with ONE change: B staged from a
// pre-PACKED layout pk[kc][4096][16] so each (g,kc) chunk is 16KB contiguous
// (R6 staged at 1KB lane stride -> transaction-bound, 2900 cyc/iter).
// pack_items kernel replaces the items fp16 cast (gather_mse uses f32 items).
//
// ws: [0,32MB) q_fp16 | [+4MB) pk packed items | [+128KB) idx[32768] i32
//     | [+1KB) partials[256]

#define D_DIM 512
#define M_ITEMS 4096
#define N_ROWS 32768
#define BM 128
#define GCOLS 512            // cols per group (B chunk width)
#define NG (M_ITEMS / GCOLS) // 8 groups
#define NKC (D_DIM / 16)     // 32 k-chunks per group
#define TOT (NG * NKC)       // 256 iterations
#define MROWS 128

typedef _Float16 half8 __attribute__((ext_vector_type(8)));
typedef _Float16 half4h __attribute__((ext_vector_type(4)));
typedef float f32x16 __attribute__((ext_vector_type(16)));

#define GLD_LDS16(g, l)                                                        \
  __builtin_amdgcn_global_load_lds(                                            \
      (__attribute__((address_space(1))) const void*)(g),                      \
      (__attribute__((address_space(3))) void*)(l), 16, 0, 0)

#define BAR() __builtin_amdgcn_s_barrier()
#define SCHEDB() __builtin_amdgcn_sched_barrier(0)
#define VMW0() asm volatile("s_waitcnt vmcnt(0)" ::: "memory")

__global__ __launch_bounds__(256) void cast_f32_f16(
    const float* __restrict__ in, _Float16* __restrict__ out, int n4) {
  const int stride = gridDim.x * blockDim.x;
  for (int i = blockIdx.x * blockDim.x + threadIdx.x; i < n4; i += stride) {
    const float4 v = reinterpret_cast<const float4*>(in)[i];
    half4h h;
    h.x = (_Float16)v.x;
    h.y = (_Float16)v.y;
    h.z = (_Float16)v.z;
    h.w = (_Float16)v.w;
    reinterpret_cast<half4h*>(out)[i] = h;
  }
}

// pk[kc][m][16]: unit u = kc*4096 + m holds items[m][kc*16 .. +16) as fp16.
// Writes coalesced (unit u at pk + u*16); reads 64B-granular strided (fine).
__global__ __launch_bounds__(256) void pack_items(
    const float* __restrict__ itf, _Float16* __restrict__ pk) {
  const int u = blockIdx.x * blockDim.x + threadIdx.x; // 0..131071
  const int kc = u >> 12;
  const int m = u & 4095;
  const float* src = itf + (size_t)m * D_DIM + kc * 16;
  float v[16];
#pragma unroll
  for (int i = 0; i < 4; ++i) {
    const float4 f = reinterpret_cast<const float4*>(src)[i];
    v[i * 4 + 0] = f.x;
    v[i * 4 + 1] = f.y;
    v[i * 4 + 2] = f.z;
    v[i * 4 + 3] = f.w;
  }
  half8 h0, h1;
#pragma unroll
  for (int i = 0; i < 8; ++i) {
    h0[i] = (_Float16)v[i];
    h1[i] = (_Float16)v[8 + i];
  }
  half8* dst = (half8*)(pk + (size_t)u * 16);
  dst[0] = h0;
  dst[1] = h1;
}

// Stage B chunk J (group J>>5, kc J&31) into Blds[buf]: contiguous 16KB src.
// LDS unit (s,c) at elem (s*512+c)*8 holds items[g*512+c][kc*16 + s*8 .. +8).
#define STAGE_B(J, buf)                                                        \
  do {                                                                         \
    const _Float16* src_ =                                                     \
        pk + ((size_t)(((J) & 31) * 4096 + ((J) >> 5) * 512 + t)) * 16;        \
    GLD_LDS16(src_, &Blds[buf][0] + t * 8);                                    \
    GLD_LDS16(src_ + 8, &Blds[buf][0] + 4096 + t * 8);                         \
  } while (0)

__global__ __launch_bounds__(512, 2) void score_argmax(
    const _Float16* __restrict__ qh, const _Float16* __restrict__ pk,
    int* __restrict__ idxArr) {
  __shared__ _Float16 Alds[BM * D_DIM]; // 128 KiB, full-K A, XOR-8 swizzled
  __shared__ _Float16 Blds[2][2 * 512 * 8]; // 2 x 16 KiB

  const int t = threadIdx.x; // 0..511
  const int lane = t & 63;
  const int wid = t >> 6;  // 0..7
  const int wm = wid >> 2; // 0..1 (row half: 64 rows)
  const int wn = wid & 3;  // 0..3 (col quarter of 512: 128 cols)
  const int l31 = lane & 31;
  const int hsel = lane >> 5; // 0..1
  const int l7 = lane & 7;

  // T1: XCD chunking (grid 256 = 8 XCD x 32)
  const int bid = blockIdx.x;
  const int rb = (bid & 7) * 32 + (bid >> 3);
  const int row0 = rb * BM;

  // --- stage A once (16 x 16B/thread = 128KB), swizzled: LDS slot (row,s)
  // holds global k-group s^(row&7). Per-GLD row is wave-uniform, slot=lane.
#pragma unroll
  for (int i = 0; i < 16; ++i) {
    const int f = i * 512 + t;
    const int r = f >> 6;
    const int s = f & 63;
    GLD_LDS16(qh + (size_t)(row0 + r) * D_DIM + ((s ^ (r & 7)) * 8),
              (_Float16*)Alds + (size_t)f * 8);
  }
  STAGE_B(0, 0);

  f32x16 acc[2][4];
#pragma unroll
  for (int fr = 0; fr < 2; ++fr)
#pragma unroll
    for (int fc = 0; fc < 4; ++fc) acc[fr][fc] = (f32x16)(0.0f);
  float rmax[2][16];
  int ridx[2][16];
#pragma unroll
  for (int fr = 0; fr < 2; ++fr)
#pragma unroll
    for (int rg = 0; rg < 16; ++rg) {
      rmax[fr][rg] = -3.0e38f;
      ridx[fr][rg] = 0;
    }

  // A-frag row element-offsets (row*512), fr=0,1; row = wm*64+fr*32+l31
  const int arow0 = (wm * 64 + l31) * D_DIM;
  const int arow1 = (wm * 64 + 32 + l31) * D_DIM;

#pragma unroll 1
  for (int J = 0; J < TOT; ++J) {
    VMW0(); // my stage of buf[J&1] (issued last iter) complete
    BAR();  // all waves' stages landed; all readers of buf[(J+1)&1] done
    SCHEDB();
    if (J + 1 < TOT) STAGE_B(J + 1, (J + 1) & 1);

    const int kc = J & 31;
    const _Float16* Bb = &Blds[J & 1][0];
    // A frags: k-group g = kc*2 + hsel, slot = g ^ (row&7); row&7 == l7
    const int aslot = ((kc * 2 + hsel) ^ l7) * 8;
    half8 af[2], bf[4];
    af[0] = *(const half8*)(Alds + arow0 + aslot);
    af[1] = *(const half8*)(Alds + arow1 + aslot);
#pragma unroll
    for (int fc = 0; fc < 4; ++fc) {
      const int c = wn * 128 + fc * 32 + l31;
      bf[fc] = *(const half8*)(Bb + (size_t)(hsel * 512 + c) * 8);
    }
#pragma unroll
    for (int fr = 0; fr < 2; ++fr)
#pragma unroll
      for (int fc = 0; fc < 4; ++fc)
        acc[fr][fc] = __builtin_amdgcn_mfma_f32_32x32x16_f16(
            af[fr], bf[fc], acc[fr][fc], 0, 0, 0);

    if (kc == 31) { // group complete: fold into per-lane running (max,idx)
      const int colbase = (J >> 5) * GCOLS + wn * 128 + l31;
#pragma unroll
      for (int fr = 0; fr < 2; ++fr)
#pragma unroll
        for (int rg = 0; rg < 16; ++rg) {
          float v = acc[fr][0][rg];
          int c = colbase;
#pragma unroll
          for (int fc = 1; fc < 4; ++fc) {
            const float vv = acc[fr][fc][rg];
            if (vv > v) { // cols ascend with fc: strict > keeps lowest
              v = vv;
              c = colbase + fc * 32;
            }
          }
          if (v > rmax[fr][rg]) { // groups ascend: strict > keeps lowest
            rmax[fr][rg] = v;
            ridx[fr][rg] = c;
          }
        }
#pragma unroll
      for (int fr = 0; fr < 2; ++fr)
#pragma unroll
        for (int fc = 0; fc < 4; ++fc) acc[fr][fc] = (f32x16)(0.0f);
    }
  }

  // --- block end: butterfly-reduce each (fr,rg) entry across the 32 col
  // lanes; lane picks its entry e = lane&31. C/D layout (m74/m101): col =
  // lane&31, row = (rg&3) + 8*(rg>>2) + 4*(lane>>5).
  float bv = -3.0e38f;
  int bi = 0;
#pragma unroll
  for (int fr = 0; fr < 2; ++fr)
#pragma unroll
    for (int rg = 0; rg < 16; ++rg) {
      float v = rmax[fr][rg];
      int c = ridx[fr][rg];
#pragma unroll
      for (int m = 1; m < 32; m <<= 1) {
        const float ov = __shfl_xor(v, m, 64);
        const int oc = __shfl_xor(c, m, 64);
        if (ov > v || (ov == v && oc < c)) {
          v = ov;
          c = oc;
        }
      }
      if (l31 == fr * 16 + rg) {
        bv = v;
        bi = c;
      }
    }
  const int e = l31;
  const int row_local =
      wm * 64 + (e >> 4) * 32 + ((e & 3) + 8 * ((e >> 2) & 3)) + 4 * hsel;

  // wn-merge via LDS (reuse B buffers; all B reads done after final barrier)
  float* sV = (float*)&Blds[0][0]; // [4][128]
  int* sI = (int*)(sV + 4 * BM);   // [4][128]
  sV[wn * BM + row_local] = bv;
  sI[wn * BM + row_local] = bi;
  __syncthreads();
  if (t < BM) {
    float fv = sV[t];
    int fi = sI[t];
#pragma unroll
    for (int w = 1; w < 4; ++w) {
      const float v = sV[w * BM + t];
      const int ii = sI[w * BM + t];
      if (v > fv || (v == fv && ii < fi)) {
        fv = v;
        fi = ii;
      }
    }
    idxArr[row0 + t] = fi;
  }
}

__global__ __launch_bounds__(256) void gather_mse(
    const float* __restrict__ qf, const float* __restrict__ itf,
    const int* __restrict__ idxArr, float* __restrict__ partials) {
  __shared__ float sSum[4];
  const int t = threadIdx.x;
  const int lane = t & 63;
  const int wv = t >> 6;
  const int row0 = blockIdx.x * MROWS;

  float lsum = 0.0f;
  for (int rr = 0; rr < 32; ++rr) {
    const int row = row0 + wv * 32 + rr;
    const int bi = idxArr[row];
    const float* qr = qf + (size_t)row * D_DIM + lane * 8;
    const float* gr = itf + (size_t)bi * D_DIM + lane * 8;
    const float4 a0 = reinterpret_cast<const float4*>(qr)[0];
    const float4 a1 = reinterpret_cast<const float4*>(qr)[1];
    const float4 b0 = reinterpret_cast<const float4*>(gr)[0];
    const float4 b1 = reinterpret_cast<const float4*>(gr)[1];
    const float d0 = a0.x - b0.x, d1 = a0.y - b0.y;
    const float d2 = a0.z - b0.z, d3 = a0.w - b0.w;
    const float d4 = a1.x - b1.x, d5 = a1.y - b1.y;
    const float d6 = a1.z - b1.z, d7 = a1.w - b1.w;
    lsum += d0 * d0 + d1 * d1 + d2 * d2 + d3 * d3 + d4 * d4 + d5 * d5 +
            d6 * d6 + d7 * d7;
  }
#pragma unroll
  for (int m = 1; m < 64; m <<= 1) lsum += __shfl_xor(lsum, m, 64);
  if (lane == 0) sSum[wv] = lsum;
  __syncthreads();
  if (t == 0) partials[blockIdx.x] = sSum[0] + sSum[1] + sSum[2] + sSum[3];
}

__global__ __launch_bounds__(256) void final_reduce(
    const float* __restrict__ partials, float* __restrict__ out) {
  __shared__ float sS[4];
  const int t = threadIdx.x;
  float v = partials[t]; // exactly 256 partials
#pragma unroll
  for (int m = 1; m < 64; m <<= 1) v += __shfl_xor(v, m, 64);
  if ((t & 63) == 0) sS[t >> 6] = v;
  __syncthreads();
  if (t == 0)
    out[0] = (sS[0] + sS[1] + sS[2] + sS[3]) *
             (1.0f / ((float)N_ROWS * (float)D_DIM));
}

extern "C" void kernel_launch(void* const* d_in, const int* in_sizes, int n_in,
                              void* d_out, int out_size, void* d_ws,
                              size_t ws_size, hipStream_t stream) {
  const float* qf = (const float*)d_in[0];  // [32768][512]
  const float* itf = (const float*)d_in[1]; // [4096][512]
  char* ws = (char*)d_ws;
  _Float16* qh = (_Float16*)ws;                                // 32 MB
  _Float16* pk = (_Float16*)(ws + (size_t)N_ROWS * D_DIM * 2); // 4 MB packed
  char* p = ws + (size_t)N_ROWS * D_DIM * 2 + (size_t)M_ITEMS * D_DIM * 2;
  int* idxArr = (int*)p;                              // 128 KB
  float* partials = (float*)(p + (size_t)N_ROWS * 4); // 1 KB
  float* out = (float*)d_out;

  cast_f32_f16<<<2048, 256, 0, stream>>>(qf, qh, N_ROWS * D_DIM / 4);
  pack_items<<<512, 256, 0, stream>>>(itf, pk);
  score_argmax<<<N_ROWS / BM, 512, 0, stream>>>(qh, pk, idxArr);
  gather_mse<<<N_ROWS / MROWS, 256, 0, stream>>>(qf, itf, idxArr, partials);
  final_reduce<<<1, 256, 0, stream>>>(partials, out);
}

// Round 8
// 190.256 us; speedup vs baseline: 1.7021x; 1.3706x over previous
//
#include <hip/hip_runtime.h>
#include <hip/hip_bf16.h>
#include <stdint.h>

// GatheringLoss: score = q[32768x512] @ items[4096x512]^T, idx = argmax_row,
// out = mean((q - items[idx])^2).
// R8: kill the serial per-iter chain (R2/R4/R7 all ~565 TF: vmcnt(0)+barrier
// +stage+ds_read serialized each iter). B fragments now load GLOBAL->REG
// directly from packed pk (each wave's 64 lanes = one contiguous 1KB region
// per fc -> single coalesced dwordx4; B is 4MB = L2-resident). Main loop has
// NO barriers, NO B LDS; manual 2-body register double-buffer (bfA/bfB) for
// 1-deep prefetch; compiler places counted waitcnts. A (q) stays full-K
// LDS-resident (128KB, XOR-8 swizzle, verified). 32x32x16 MFMA, 256 iters.
//
// ws: [0,32MB) q_fp16 | [+4MB) pk packed items | [+128KB) idx[32768] i32
//     | [+1KB) partials[256]

#define D_DIM 512
#define M_ITEMS 4096
#define N_ROWS 32768
#define BM 128
#define GCOLS 512            // cols per group
#define NG (M_ITEMS / GCOLS) // 8 groups
#define NKC (D_DIM / 16)     // 32 k-chunks per group
#define TOT (NG * NKC)       // 256 iterations
#define MROWS 128

typedef _Float16 half8 __attribute__((ext_vector_type(8)));
typedef _Float16 half4h __attribute__((ext_vector_type(4)));
typedef float f32x16 __attribute__((ext_vector_type(16)));

#define GLD_LDS16(g, l)                                                        \
  __builtin_amdgcn_global_load_lds(                                            \
      (__attribute__((address_space(1))) const void*)(g),                      \
      (__attribute__((address_space(3))) void*)(l), 16, 0, 0)

__global__ __launch_bounds__(256) void cast_f32_f16(
    const float* __restrict__ in, _Float16* __restrict__ out, int n4) {
  const int stride = gridDim.x * blockDim.x;
  for (int i = blockIdx.x * blockDim.x + threadIdx.x; i < n4; i += stride) {
    const float4 v = reinterpret_cast<const float4*>(in)[i];
    half4h h;
    h.x = (_Float16)v.x;
    h.y = (_Float16)v.y;
    h.z = (_Float16)v.z;
    h.w = (_Float16)v.w;
    reinterpret_cast<half4h*>(out)[i] = h;
  }
}

// pk[kc][m][16]: unit u = kc*4096 + m holds items[m][kc*16 .. +16) as fp16.
__global__ __launch_bounds__(256) void pack_items(
    const float* __restrict__ itf, _Float16* __restrict__ pk) {
  const int u = blockIdx.x * blockDim.x + threadIdx.x; // 0..131071
  const int kc = u >> 12;
  const int m = u & 4095;
  const float* src = itf + (size_t)m * D_DIM + kc * 16;
  float v[16];
#pragma unroll
  for (int i = 0; i < 4; ++i) {
    const float4 f = reinterpret_cast<const float4*>(src)[i];
    v[i * 4 + 0] = f.x;
    v[i * 4 + 1] = f.y;
    v[i * 4 + 2] = f.z;
    v[i * 4 + 3] = f.w;
  }
  half8 h0, h1;
#pragma unroll
  for (int i = 0; i < 8; ++i) {
    h0[i] = (_Float16)v[i];
    h1[i] = (_Float16)v[8 + i];
  }
  half8* dst = (half8*)(pk + (size_t)u * 16);
  dst[0] = h0;
  dst[1] = h1;
}

__global__ __launch_bounds__(512, 2) void score_argmax(
    const _Float16* __restrict__ qh, const _Float16* __restrict__ pk,
    int* __restrict__ idxArr) {
  __shared__ _Float16 Alds[BM * D_DIM]; // 128 KiB, full-K A, XOR-8 swizzled
  __shared__ float sV[4][BM];           // 2 KiB
  __shared__ int sI[4][BM];             // 2 KiB

  const int t = threadIdx.x; // 0..511
  const int lane = t & 63;
  const int wid = t >> 6;  // 0..7
  const int wm = wid >> 2; // 0..1 (row half: 64 rows)
  const int wn = wid & 3;  // 0..3 (col quarter of 512: 128 cols)
  const int l31 = lane & 31;
  const int hsel = lane >> 5; // 0..1
  const int l7 = lane & 7;

  // T1: XCD chunking (grid 256 = 8 XCD x 32)
  const int bid = blockIdx.x;
  const int rb = (bid & 7) * 32 + (bid >> 3);
  const int row0 = rb * BM;

  // --- stage A once (16 x 16B/thread = 128KB), swizzled: LDS slot (row,s)
  // holds global k-group s^(row&7).
#pragma unroll
  for (int i = 0; i < 16; ++i) {
    const int f = i * 512 + t;
    const int r = f >> 6;
    const int s = f & 63;
    GLD_LDS16(qh + (size_t)(row0 + r) * D_DIM + ((s ^ (r & 7)) * 8),
              (_Float16*)Alds + (size_t)f * 8);
  }
  asm volatile("s_waitcnt vmcnt(0)" ::: "memory");
  __syncthreads();

  f32x16 acc[2][4];
#pragma unroll
  for (int fr = 0; fr < 2; ++fr)
#pragma unroll
    for (int fc = 0; fc < 4; ++fc) acc[fr][fc] = (f32x16)(0.0f);
  float rmax[2][16];
  int ridx[2][16];
#pragma unroll
  for (int fr = 0; fr < 2; ++fr)
#pragma unroll
    for (int rg = 0; rg < 16; ++rg) {
      rmax[fr][rg] = -3.0e38f;
      ridx[fr][rg] = 0;
    }

  // A-frag row element-offsets (row*512); row&7 == l7 for both rows.
  const int arow0 = (wm * 64 + l31) * D_DIM;
  const int arow1 = (wm * 64 + 32 + l31) * D_DIM;
  // B per-thread base: elem addr = ((kc*4096 + g*512 + wn*128 + fc*32 + l31)
  //                                 * 16) + hsel*8
  const _Float16* bbase = pk + ((size_t)(wn * 128 + l31) << 4) + hsel * 8;

// load B frags for iteration J into reg set BF (4 coalesced dwordx4/wave)
#define LOADB(J, BF)                                                           \
  do {                                                                         \
    const int g_ = (J) >> 5, kc_ = (J) & 31;                                   \
    const _Float16* p_ = bbase + (((size_t)kc_ * 4096 + g_ * 512) << 4);       \
    BF[0] = *(const half8*)(p_);                                               \
    BF[1] = *(const half8*)(p_ + (32 << 4));                                   \
    BF[2] = *(const half8*)(p_ + (64 << 4));                                   \
    BF[3] = *(const half8*)(p_ + (96 << 4));                                   \
  } while (0)

// one iteration: prefetch J+1 into BN, compute J with BC, fold at group end
#define BODY(J, BC, BN)                                                        \
  do {                                                                         \
    if ((J) + 1 < TOT) LOADB((J) + 1, BN);                                     \
    const int kc_ = (J) & 31;                                                  \
    const int aslot_ = ((kc_ * 2 + hsel) ^ l7) * 8;                            \
    half8 af0_ = *(const half8*)(Alds + arow0 + aslot_);                       \
    half8 af1_ = *(const half8*)(Alds + arow1 + aslot_);                       \
    _Pragma("unroll") for (int fc = 0; fc < 4; ++fc) {                         \
      acc[0][fc] = __builtin_amdgcn_mfma_f32_32x32x16_f16(af0_, BC[fc],        \
                                                          acc[0][fc], 0, 0, 0);\
      acc[1][fc] = __builtin_amdgcn_mfma_f32_32x32x16_f16(af1_, BC[fc],        \
                                                          acc[1][fc], 0, 0, 0);\
    }                                                                          \
    if (kc_ == 31) {                                                           \
      const int colbase_ = ((J) >> 5) * GCOLS + wn * 128 + l31;                \
      _Pragma("unroll") for (int fr = 0; fr < 2; ++fr)                         \
          _Pragma("unroll") for (int rg = 0; rg < 16; ++rg) {                  \
        float v_ = acc[fr][0][rg];                                             \
        int c_ = colbase_;                                                     \
        _Pragma("unroll") for (int fc = 1; fc < 4; ++fc) {                     \
          const float vv_ = acc[fr][fc][rg];                                   \
          if (vv_ > v_) {                                                      \
            v_ = vv_;                                                          \
            c_ = colbase_ + fc * 32;                                           \
          }                                                                    \
        }                                                                      \
        if (v_ > rmax[fr][rg]) {                                               \
          rmax[fr][rg] = v_;                                                   \
          ridx[fr][rg] = c_;                                                   \
        }                                                                      \
      }                                                                        \
      _Pragma("unroll") for (int fr = 0; fr < 2; ++fr)                         \
          _Pragma("unroll") for (int fc = 0; fc < 4; ++fc) acc[fr][fc] =       \
              (f32x16)(0.0f);                                                  \
    }                                                                          \
  } while (0)

  half8 bfA[4], bfB[4];
  LOADB(0, bfA);
#pragma unroll 1
  for (int J = 0; J < TOT; J += 2) {
    BODY(J, bfA, bfB);
    BODY(J + 1, bfB, bfA);
  }

  // --- block end: butterfly-reduce each (fr,rg) entry across the 32 col
  // lanes; lane picks its entry e = lane&31. C/D layout (m74/m101): col =
  // lane&31, row = (rg&3) + 8*(rg>>2) + 4*(lane>>5).
  float bv = -3.0e38f;
  int bi = 0;
#pragma unroll
  for (int fr = 0; fr < 2; ++fr)
#pragma unroll
    for (int rg = 0; rg < 16; ++rg) {
      float v = rmax[fr][rg];
      int c = ridx[fr][rg];
#pragma unroll
      for (int m = 1; m < 32; m <<= 1) {
        const float ov = __shfl_xor(v, m, 64);
        const int oc = __shfl_xor(c, m, 64);
        if (ov > v || (ov == v && oc < c)) {
          v = ov;
          c = oc;
        }
      }
      if (l31 == fr * 16 + rg) {
        bv = v;
        bi = c;
      }
    }
  const int e = l31;
  const int row_local =
      wm * 64 + (e >> 4) * 32 + ((e & 3) + 8 * ((e >> 2) & 3)) + 4 * hsel;

  sV[wn][row_local] = bv;
  sI[wn][row_local] = bi;
  __syncthreads();
  if (t < BM) {
    float fv = sV[0][t];
    int fi = sI[0][t];
#pragma unroll
    for (int w = 1; w < 4; ++w) {
      const float v = sV[w][t];
      const int ii = sI[w][t];
      if (v > fv || (v == fv && ii < fi)) {
        fv = v;
        fi = ii;
      }
    }
    idxArr[row0 + t] = fi;
  }
}

__global__ __launch_bounds__(256) void gather_mse(
    const float* __restrict__ qf, const float* __restrict__ itf,
    const int* __restrict__ idxArr, float* __restrict__ partials) {
  __shared__ float sSum[4];
  const int t = threadIdx.x;
  const int lane = t & 63;
  const int wv = t >> 6;
  const int row0 = blockIdx.x * MROWS;

  float lsum = 0.0f;
  for (int rr = 0; rr < 32; ++rr) {
    const int row = row0 + wv * 32 + rr;
    const int bi = idxArr[row];
    const float* qr = qf + (size_t)row * D_DIM + lane * 8;
    const float* gr = itf + (size_t)bi * D_DIM + lane * 8;
    const float4 a0 = reinterpret_cast<const float4*>(qr)[0];
    const float4 a1 = reinterpret_cast<const float4*>(qr)[1];
    const float4 b0 = reinterpret_cast<const float4*>(gr)[0];
    const float4 b1 = reinterpret_cast<const float4*>(gr)[1];
    const float d0 = a0.x - b0.x, d1 = a0.y - b0.y;
    const float d2 = a0.z - b0.z, d3 = a0.w - b0.w;
    const float d4 = a1.x - b1.x, d5 = a1.y - b1.y;
    const float d6 = a1.z - b1.z, d7 = a1.w - b1.w;
    lsum += d0 * d0 + d1 * d1 + d2 * d2 + d3 * d3 + d4 * d4 + d5 * d5 +
            d6 * d6 + d7 * d7;
  }
#pragma unroll
  for (int m = 1; m < 64; m <<= 1) lsum += __shfl_xor(lsum, m, 64);
  if (lane == 0) sSum[wv] = lsum;
  __syncthreads();
  if (t == 0) partials[blockIdx.x] = sSum[0] + sSum[1] + sSum[2] + sSum[3];
}

__global__ __launch_bounds__(256) void final_reduce(
    const float* __restrict__ partials, float* __restrict__ out) {
  __shared__ float sS[4];
  const int t = threadIdx.x;
  float v = partials[t]; // exactly 256 partials
#pragma unroll
  for (int m = 1; m < 64; m <<= 1) v += __shfl_xor(v, m, 64);
  if ((t & 63) == 0) sS[t >> 6] = v;
  __syncthreads();
  if (t == 0)
    out[0] = (sS[0] + sS[1] + sS[2] + sS[3]) *
             (1.0f / ((float)N_ROWS * (float)D_DIM));
}

extern "C" void kernel_launch(void* const* d_in, const int* in_sizes, int n_in,
                              void* d_out, int out_size, void* d_ws,
                              size_t ws_size, hipStream_t stream) {
  const float* qf = (const float*)d_in[0];  // [32768][512]
  const float* itf = (const float*)d_in[1]; // [4096][512]
  char* ws = (char*)d_ws;
  _Float16* qh = (_Float16*)ws;                                // 32 MB
  _Float16* pk = (_Float16*)(ws + (size_t)N_ROWS * D_DIM * 2); // 4 MB packed
  char* p = ws + (size_t)N_ROWS * D_DIM * 2 + (size_t)M_ITEMS * D_DIM * 2;
  int* idxArr = (int*)p;                              // 128 KB
  float* partials = (float*)(p + (size_t)N_ROWS * 4); // 1 KB
  float* out = (float*)d_out;

  cast_f32_f16<<<2048, 256, 0, stream>>>(qf, qh, N_ROWS * D_DIM / 4);
  pack_items<<<512, 256, 0, stream>>>(itf, pk);
  score_argmax<<<N_ROWS / BM, 512, 0, stream>>>(qh, pk, idxArr);
  gather_mse<<<N_ROWS / MROWS, 256, 0, stream>>>(qf, itf, idxArr, partials);
  final_reduce<<<1, 256, 0, stream>>>(partials, out);
}

// Round 9
// 171.354 us; speedup vs baseline: 1.8899x; 1.1103x over previous
//
#include <hip/hip_runtime.h>
#include <hip/hip_bf16.h>
#include <stdint.h>

// GatheringLoss: score = q[32768x512] @ items[4096x512]^T, idx = argmax_row,
// out = mean((q - items[idx])^2).
// R9 (on R8's barrier-free global->reg B): 
//  - depth-2 B prefetch (3 reg sets, rotation static per rule #20), paid for
//    by 16-bit-packed ridx (idx<4096: 2 per VGPR, -16 regs).
//  - setprio(1) around MFMA cluster (wave role-diversity exists: no barriers).
//  - fused q-cast prologue (block casts its own 128 rows f32->fp16 into Alds
//    via ds_write; qh buffer + cast kernel for q deleted).
//  - fused MSE epilogue from Alds (fp16 q) + linear fp16 items (ihl);
//    gather_mse + idxArr deleted. Bias ~1e-3 << 3.4e-2 threshold.
// ws: [0,4MB) pk packed items | [+4MB) ihl fp16 linear items | [+1KB) partials

#define D_DIM 512
#define M_ITEMS 4096
#define N_ROWS 32768
#define BM 128
#define GCOLS 512            // cols per group
#define NG (M_ITEMS / GCOLS) // 8 groups
#define NKC (D_DIM / 16)     // 32 k-chunks per group
#define TOT (NG * NKC)       // 256 iterations

typedef _Float16 half8 __attribute__((ext_vector_type(8)));
typedef _Float16 half4h __attribute__((ext_vector_type(4)));
typedef float f32x16 __attribute__((ext_vector_type(16)));

__global__ __launch_bounds__(256) void cast_f32_f16(
    const float* __restrict__ in, _Float16* __restrict__ out, int n4) {
  const int stride = gridDim.x * blockDim.x;
  for (int i = blockIdx.x * blockDim.x + threadIdx.x; i < n4; i += stride) {
    const float4 v = reinterpret_cast<const float4*>(in)[i];
    half4h h;
    h.x = (_Float16)v.x;
    h.y = (_Float16)v.y;
    h.z = (_Float16)v.z;
    h.w = (_Float16)v.w;
    reinterpret_cast<half4h*>(out)[i] = h;
  }
}

// pk[kc][m][16] from linear fp16 ihl (L2-hot 4MB): unit u = kc*4096+m.
__global__ __launch_bounds__(256) void pack_items(
    const _Float16* __restrict__ ihl, _Float16* __restrict__ pk) {
  const int u = blockIdx.x * blockDim.x + threadIdx.x; // 0..131071
  const int kc = u >> 12;
  const int m = u & 4095;
  const half8* src = (const half8*)(ihl + (size_t)m * D_DIM + kc * 16);
  half8* dst = (half8*)(pk + (size_t)u * 16);
  dst[0] = src[0];
  dst[1] = src[1];
}

__global__ __launch_bounds__(512, 2) void score_mse(
    const float* __restrict__ qf, const _Float16* __restrict__ pk,
    const _Float16* __restrict__ ihl, float* __restrict__ partials) {
  __shared__ _Float16 Alds[BM * D_DIM]; // 128 KiB, full-K A, XOR-8 swizzled
  __shared__ float sV[4][BM];           // 2 KiB
  __shared__ int sI[4][BM];             // 2 KiB
  __shared__ float sSum[8];

  const int t = threadIdx.x; // 0..511
  const int lane = t & 63;
  const int wid = t >> 6;  // 0..7
  const int wm = wid >> 2; // 0..1 (row half: 64 rows)
  const int wn = wid & 3;  // 0..3 (col quarter of 512: 128 cols)
  const int l31 = lane & 31;
  const int hsel = lane >> 5; // 0..1
  const int l7 = lane & 7;

  // T1: XCD chunking (grid 256 = 8 XCD x 32)
  const int bid = blockIdx.x;
  const int rb = (bid & 7) * 32 + (bid >> 3);
  const int row0 = rb * BM;

  // --- prologue: cast this block's 128 q rows f32->fp16 into Alds, swizzled:
  // LDS unit (r,u) holds global k-unit u^(r&7). Thread handles unit f=i*512+t:
  // loads the GLOBAL unit (s^(r&7)) so LDS stays write-linear... (ds_write is
  // per-lane scattered-capable; we write linear f anyway).
#pragma unroll
  for (int i = 0; i < 16; ++i) {
    const int f = i * 512 + t;
    const int r = f >> 6;
    const int s = f & 63;
    const float* src = qf + (size_t)(row0 + r) * D_DIM + ((s ^ (r & 7)) * 8);
    const float4 a = reinterpret_cast<const float4*>(src)[0];
    const float4 b = reinterpret_cast<const float4*>(src)[1];
    half8 h;
    h[0] = (_Float16)a.x; h[1] = (_Float16)a.y;
    h[2] = (_Float16)a.z; h[3] = (_Float16)a.w;
    h[4] = (_Float16)b.x; h[5] = (_Float16)b.y;
    h[6] = (_Float16)b.z; h[7] = (_Float16)b.w;
    *(half8*)(Alds + (size_t)f * 8) = h;
  }
  __syncthreads();

  f32x16 acc[2][4];
#pragma unroll
  for (int fr = 0; fr < 2; ++fr)
#pragma unroll
    for (int fc = 0; fc < 4; ++fc) acc[fr][fc] = (f32x16)(0.0f);
  float rmax[2][16];
  unsigned rid16[16]; // packed idx: bits [15:0]=fr0, [31:16]=fr1
#pragma unroll
  for (int rg = 0; rg < 16; ++rg) {
    rmax[0][rg] = -3.0e38f;
    rmax[1][rg] = -3.0e38f;
    rid16[rg] = 0u;
  }

  // A-frag row element-offsets; row&7 == l7 for both rows.
  const int arow0 = (wm * 64 + l31) * D_DIM;
  const int arow1 = (wm * 64 + 32 + l31) * D_DIM;
  const _Float16* bbase = pk + ((size_t)(wn * 128 + l31) << 4) + hsel * 8;

#define LOADB(J, BF)                                                           \
  do {                                                                         \
    const int g_ = (J) >> 5, kc_ = (J) & 31;                                   \
    const _Float16* p_ = bbase + (((size_t)kc_ * 4096 + g_ * 512) << 4);       \
    BF[0] = *(const half8*)(p_);                                               \
    BF[1] = *(const half8*)(p_ + (32 << 4));                                   \
    BF[2] = *(const half8*)(p_ + (64 << 4));                                   \
    BF[3] = *(const half8*)(p_ + (96 << 4));                                   \
  } while (0)

// compute J with BC; issue load of J+2 into BN (depth-2, 3 rotating sets)
#define BODY(J, BC, BN)                                                        \
  do {                                                                         \
    if ((J) + 2 < TOT) LOADB((J) + 2, BN);                                     \
    const int kc_ = (J) & 31;                                                  \
    const int aslot_ = ((kc_ * 2 + hsel) ^ l7) * 8;                            \
    half8 af0_ = *(const half8*)(Alds + arow0 + aslot_);                       \
    half8 af1_ = *(const half8*)(Alds + arow1 + aslot_);                       \
    __builtin_amdgcn_s_setprio(1);                                             \
    _Pragma("unroll") for (int fc = 0; fc < 4; ++fc) {                         \
      acc[0][fc] = __builtin_amdgcn_mfma_f32_32x32x16_f16(af0_, BC[fc],        \
                                                          acc[0][fc], 0, 0, 0);\
      acc[1][fc] = __builtin_amdgcn_mfma_f32_32x32x16_f16(af1_, BC[fc],        \
                                                          acc[1][fc], 0, 0, 0);\
    }                                                                          \
    __builtin_amdgcn_s_setprio(0);                                             \
    if (kc_ == 31) {                                                           \
      const int colbase_ = ((J) >> 5) * GCOLS + wn * 128 + l31;                \
      _Pragma("unroll") for (int fr = 0; fr < 2; ++fr)                         \
          _Pragma("unroll") for (int rg = 0; rg < 16; ++rg) {                  \
        float v_ = acc[fr][0][rg];                                             \
        int c_ = colbase_;                                                     \
        _Pragma("unroll") for (int fc = 1; fc < 4; ++fc) {                     \
          const float vv_ = acc[fr][fc][rg];                                   \
          if (vv_ > v_) {                                                      \
            v_ = vv_;                                                          \
            c_ = colbase_ + fc * 32;                                           \
          }                                                                    \
        }                                                                      \
        if (v_ > rmax[fr][rg]) {                                               \
          rmax[fr][rg] = v_;                                                   \
          rid16[rg] = (rid16[rg] & (fr ? 0x0000FFFFu : 0xFFFF0000u)) |         \
                      ((unsigned)c_ << (fr * 16));                             \
        }                                                                      \
      }                                                                        \
      _Pragma("unroll") for (int fr = 0; fr < 2; ++fr)                         \
          _Pragma("unroll") for (int fc = 0; fc < 4; ++fc) acc[fr][fc] =       \
              (f32x16)(0.0f);                                                  \
    }                                                                          \
  } while (0)

  half8 bf0[4], bf1[4], bf2[4];
  LOADB(0, bf0);
  LOADB(1, bf1);
#pragma unroll 1
  for (int J = 0; J < 255; J += 3) { // 85 triples = J 0..254
    BODY(J, bf0, bf2);
    BODY(J + 1, bf1, bf0);
    BODY(J + 2, bf2, bf1);
  }
  BODY(255, bf0, bf1); // tail (load guarded off)

  // --- argmax block reduce. C/D layout (m74/m101): col = lane&31,
  // row = (rg&3) + 8*(rg>>2) + 4*(lane>>5).
  float bv = -3.0e38f;
  int bi = 0;
#pragma unroll
  for (int fr = 0; fr < 2; ++fr)
#pragma unroll
    for (int rg = 0; rg < 16; ++rg) {
      float v = rmax[fr][rg];
      int c = (int)((rid16[rg] >> (fr * 16)) & 0xFFFFu);
#pragma unroll
      for (int m = 1; m < 32; m <<= 1) {
        const float ov = __shfl_xor(v, m, 64);
        const int oc = __shfl_xor(c, m, 64);
        if (ov > v || (ov == v && oc < c)) {
          v = ov;
          c = oc;
        }
      }
      if (l31 == fr * 16 + rg) {
        bv = v;
        bi = c;
      }
    }
  const int e = l31;
  const int row_local =
      wm * 64 + (e >> 4) * 32 + ((e & 3) + 8 * ((e >> 2) & 3)) + 4 * hsel;

  sV[wn][row_local] = bv;
  sI[wn][row_local] = bi;
  __syncthreads();
  if (t < BM) {
    float fv = sV[0][t];
    int fi = sI[0][t];
#pragma unroll
    for (int w = 1; w < 4; ++w) {
      const float v = sV[w][t];
      const int ii = sI[w][t];
      if (v > fv || (v == fv && ii < fi)) {
        fv = v;
        fi = ii;
      }
    }
    sI[0][t] = fi; // merged winner per row
  }
  __syncthreads();

  // --- fused MSE epilogue: wave wv handles rows wv*16..+15. q from Alds
  // (fp16, swizzled: lane l reads unit l^(r&7) = global elems l*8..+7),
  // gathered item from linear fp16 ihl. f32 accumulate.
  float lsum = 0.0f;
#pragma unroll 1
  for (int rr = 0; rr < 16; ++rr) {
    const int r = wid * 16 + rr;
    const int fi = sI[0][r];
    const half8 aq =
        *(const half8*)(Alds + (size_t)(r * 64 + (lane ^ (r & 7))) * 8);
    const half8 ag = *(const half8*)(ihl + (size_t)fi * D_DIM + lane * 8);
#pragma unroll
    for (int k = 0; k < 8; ++k) {
      const float d = (float)aq[k] - (float)ag[k];
      lsum += d * d;
    }
  }
#pragma unroll
  for (int m = 1; m < 64; m <<= 1) lsum += __shfl_xor(lsum, m, 64);
  if (lane == 0) sSum[wid] = lsum;
  __syncthreads();
  if (t == 0) {
    float s = 0.0f;
#pragma unroll
    for (int w = 0; w < 8; ++w) s += sSum[w];
    partials[bid] = s;
  }
}

__global__ __launch_bounds__(256) void final_reduce(
    const float* __restrict__ partials, float* __restrict__ out) {
  __shared__ float sS[4];
  const int t = threadIdx.x;
  float v = partials[t]; // exactly 256 partials
#pragma unroll
  for (int m = 1; m < 64; m <<= 1) v += __shfl_xor(v, m, 64);
  if ((t & 63) == 0) sS[t >> 6] = v;
  __syncthreads();
  if (t == 0)
    out[0] = (sS[0] + sS[1] + sS[2] + sS[3]) *
             (1.0f / ((float)N_ROWS * (float)D_DIM));
}

extern "C" void kernel_launch(void* const* d_in, const int* in_sizes, int n_in,
                              void* d_out, int out_size, void* d_ws,
                              size_t ws_size, hipStream_t stream) {
  const float* qf = (const float*)d_in[0];  // [32768][512]
  const float* itf = (const float*)d_in[1]; // [4096][512]
  char* ws = (char*)d_ws;
  _Float16* pk = (_Float16*)ws;                                   // 4 MB
  _Float16* ihl = (_Float16*)(ws + (size_t)M_ITEMS * D_DIM * 2);  // 4 MB
  float* partials = (float*)(ws + (size_t)2 * M_ITEMS * D_DIM * 2); // 1 KB
  float* out = (float*)d_out;

  cast_f32_f16<<<512, 256, 0, stream>>>(itf, ihl, M_ITEMS * D_DIM / 4);
  pack_items<<<512, 256, 0, stream>>>(ihl, pk);
  score_mse<<<N_ROWS / BM, 512, 0, stream>>>(qf, pk, ihl, partials);
  final_reduce<<<1, 256, 0, stream>>>(partials, out);
}